// Round 15
// baseline (519.987 us; speedup 1.0000x reference)
//
#include <hip/hip_runtime.h>
#include <hip/hip_fp16.h>

#define NN 100000
#define NE 3200000
#define H  64

#define BSHIFT 7
#define BNODES 128
#define NB ((NN + BNODES - 1) / BNODES)          // 782 buckets

#define PTHREADS 1024
#define PCHUNK   8192
#define PEPT     (PCHUNK / PTHREADS)             // 8
#define NPBLK    ((NE + PCHUNK - 1) / PCHUNK)    // 391 partition blocks

#define ENCB (NN / 16)                           // 6250 encoder blocks (16 nodes @1024thr)

#define ECAP 6144                                // fixed per-bucket slot (mean 4092, sd ~64)

// ---- dispatch 2: heterogeneous — partition blocks [0,NPBLK) + encoder blocks ----
__global__ __launch_bounds__(1024) void enc_part_kernel(
    const float* __restrict__ x,
    const float* __restrict__ W1, const float* __restrict__ b1,
    const float* __restrict__ W2, const float* __restrict__ b2,
    const int* __restrict__ src, const int* __restrict__ dst,
    int* __restrict__ bfill, unsigned* __restrict__ staging,
    __half* __restrict__ h16)
{
    // partition LDS (verified R9/R14 body)
    __shared__ unsigned stage[PCHUNK];   // 32 KB
    __shared__ int gpos[PCHUNK];         // 32 KB
    __shared__ int lh[NB];
    __shared__ int lcur[NB];
    __shared__ int gbase[NB];
    __shared__ int wtot[16];
    // encoder LDS
    __shared__ float sh1[16][H];         // 4 KB

    const int t = threadIdx.x;

    if (blockIdx.x < NPBLK) {
        // ---------------- partition path (verified R14, byte-identical body) --------
        const int lane = t & 63;
        const int wid  = t >> 6;
        const int cbase = blockIdx.x * PCHUNK;
        const int cnt = min(PCHUNK, NE - cbase);

        for (int i = t; i < NB; i += PTHREADS) lh[i] = 0;
        __syncthreads();

        unsigned ent[PEPT];
        int bkt[PEPT];
        #pragma unroll
        for (int j = 0; j < PEPT; ++j) {
            const int idx = t + j * PTHREADS;
            if (idx < cnt) {
                const int s_ = src[cbase + idx];
                const int d_ = dst[cbase + idx];
                bkt[j] = s_ >> BSHIFT;
                ent[j] = (unsigned)d_ | ((unsigned)(s_ & (BNODES - 1)) << 17);
                atomicAdd(&lh[bkt[j]], 1);
            } else bkt[j] = -1;
        }
        __syncthreads();

        const int hv = (t < NB) ? lh[t] : 0;
        int incl = hv;
        #pragma unroll
        for (int off = 1; off < 64; off <<= 1) {
            const int n = __shfl_up(incl, off);
            if (lane >= off) incl += n;
        }
        if (lane == 63) wtot[wid] = incl;
        __syncthreads();
        if (wid == 0 && lane < 16) {
            const int v = wtot[lane];
            int s2 = v;
            #pragma unroll
            for (int off = 1; off < 16; off <<= 1) {
                const int n = __shfl_up(s2, off);
                if (lane >= off) s2 += n;
            }
            wtot[lane] = s2 - v;    // exclusive wave offsets
        }
        __syncthreads();
        if (t < NB) {
            const int excl = incl - hv + wtot[wid];
            lh[t]   = excl;
            lcur[t] = excl;
            gbase[t] = t * ECAP + ((hv > 0) ? atomicAdd(&bfill[t], hv) : 0);
        }
        __syncthreads();

        #pragma unroll
        for (int j = 0; j < PEPT; ++j) {
            if (bkt[j] >= 0) {
                const int lp = atomicAdd(&lcur[bkt[j]], 1);
                stage[lp] = ent[j];
                gpos[lp]  = gbase[bkt[j]] + (lp - lh[bkt[j]]);
            }
        }
        __syncthreads();

        for (int i = t; i < cnt; i += PTHREADS)
            staging[gpos[i]] = stage[i];
    } else {
        // ---------------- encoder path (verified math; 16 nodes/block) --------------
        const int slot = t >> 6;
        const int f    = t & 63;
        const int node = (blockIdx.x - NPBLK) * 16 + slot;   // < NN always
        {
            float acc = b1[f];
            #pragma unroll
            for (int k = 0; k < 6; ++k)
                acc = fmaf(x[node * 6 + k], W1[k * H + f], acc);
            sh1[slot][f] = fmaxf(acc, 0.0f);
        }
        __syncthreads();
        {
            float acc = b2[f];
            #pragma unroll 8
            for (int k = 0; k < H; ++k)
                acc = fmaf(sh1[slot][k], W2[k * H + f], acc);
            h16[node * H + f] = __float2half(acc);
        }
    }
}

// ---- dispatch 3: bucket sort (verified R14 body, LDS-resident) + gather + MLP ----
__global__ __launch_bounds__(1024) void sort_gather_kernel(
    const __half* __restrict__ h16,
    const int* __restrict__ bfill, const unsigned* __restrict__ staging,
    const float* __restrict__ Wf1, const float* __restrict__ bf1,
    const float* __restrict__ Wf2, const float* __restrict__ bf2,
    const float* __restrict__ Ws1, const float* __restrict__ bs1,
    const float* __restrict__ Ws2, const float* __restrict__ bs2,
    const float* __restrict__ Wt1, const float* __restrict__ bt1,
    const float* __restrict__ Wt2, const float* __restrict__ bt2,
    float* __restrict__ out_scores, float* __restrict__ out_types)
{
    __shared__ int ldst[ECAP];           // 24 KB node-ordered edge targets
    __shared__ int cntS[BNODES];
    __shared__ int scanS[BNODES];
    __shared__ int lstart[BNODES];
    __shared__ int lcur[BNODES];
    __shared__ __align__(16) float sa[16][H];   // 4 KB per-wave MLP buffers
    __shared__ __align__(16) float sb[16][H];   // 4 KB
    const int t = threadIdx.x;
    const int b = blockIdx.x;
    const int base0 = b * ECAP;
    const int ecnt  = bfill[b];

    // ---- sort phase (byte-identical logic to R14-verified bucket_sort) ----
    if (t < BNODES) cntS[t] = 0;
    __syncthreads();
    for (int i = t; i < ecnt; i += 1024)
        atomicAdd(&cntS[staging[base0 + i] >> 17], 1);
    __syncthreads();
    if (t < BNODES) scanS[t] = cntS[t];
    __syncthreads();
    for (int off = 1; off < BNODES; off <<= 1) {
        int xv = 0;
        if (t >= off && t < BNODES) xv = scanS[t - off];
        __syncthreads();
        if (t >= off && t < BNODES) scanS[t] += xv;
        __syncthreads();
    }
    if (t < BNODES) {
        const int st = scanS[t] - cntS[t];
        lstart[t] = st;
        lcur[t]   = st;
    }
    __syncthreads();
    for (int i = t; i < ecnt; i += 1024) {
        const unsigned ev = staging[base0 + i];
        const int lp = atomicAdd(&lcur[(int)(ev >> 17)], 1);
        ldst[lp] = (int)(ev & 0x1FFFFu);
    }
    __syncthreads();

    // ---- gather + MLP phase (R9-verified 16-deep loop; R10-verified per-wave MLP) --
    const int w = t >> 6;
    const int f = t & 63;

    for (int n = w; n < BNODES; n += 16) {       // 8 nodes per wave
        const int node = b * BNODES + n;
        if (node >= NN) break;                   // wave-uniform, ascending
        const int deg = cntS[n];
        const int sl  = lstart[n];

        const float selfv = __half2float(h16[((size_t)node << 6) + f]);

        float acc = 0.0f;
        int jj = 0;
        for (; jj + 16 <= deg; jj += 16) {       // 16 uniform rows in flight
            __half hv[16];
            #pragma unroll
            for (int u = 0; u < 16; ++u) {
                const int d = ldst[sl + jj + u]; // wave-uniform LDS broadcast
                hv[u] = h16[((size_t)d << 6) + f];
            }
            #pragma unroll
            for (int u = 0; u < 16; ++u)
                acc += __half2float(hv[u]);
        }
        if (jj + 8 <= deg) {                     // 8-deep tail
            __half hv[8];
            #pragma unroll
            for (int u = 0; u < 8; ++u) {
                const int d = ldst[sl + jj + u];
                hv[u] = h16[((size_t)d << 6) + f];
            }
            #pragma unroll
            for (int u = 0; u < 8; ++u)
                acc += __half2float(hv[u]);
            jj += 8;
        }
        for (; jj < deg; ++jj) {
            const int d = ldst[sl + jj];
            acc += __half2float(h16[((size_t)d << 6) + f]);
        }

        const float inv = 1.0f / fmaxf((float)deg, 1.0f);
        sa[w][f] = selfv + acc * inv;            // wave-lockstep LDS (R10-verified)

        // f1: sa -> sb
        {
            float a2 = bf1[f];
            const float4* xr = (const float4*)sa[w];
            #pragma unroll 4
            for (int k4 = 0; k4 < 16; ++k4) {
                const float4 xq = xr[k4];
                const int k = k4 * 4;
                a2 = fmaf(xq.x, Wf1[(k + 0) * H + f], a2);
                a2 = fmaf(xq.y, Wf1[(k + 1) * H + f], a2);
                a2 = fmaf(xq.z, Wf1[(k + 2) * H + f], a2);
                a2 = fmaf(xq.w, Wf1[(k + 3) * H + f], a2);
            }
            sb[w][f] = fmaxf(a2, 0.0f);
        }
        // f2: sb -> sa
        {
            float a2 = bf2[f];
            const float4* xr = (const float4*)sb[w];
            #pragma unroll 4
            for (int k4 = 0; k4 < 16; ++k4) {
                const float4 xq = xr[k4];
                const int k = k4 * 4;
                a2 = fmaf(xq.x, Wf2[(k + 0) * H + f], a2);
                a2 = fmaf(xq.y, Wf2[(k + 1) * H + f], a2);
                a2 = fmaf(xq.z, Wf2[(k + 2) * H + f], a2);
                a2 = fmaf(xq.w, Wf2[(k + 3) * H + f], a2);
            }
            sa[w][f] = fmaxf(a2, 0.0f);
        }
        // heads stage 1: sa -> sb
        {
            const float4* xr = (const float4*)sa[w];
            if (f < 32) {
                float a2 = bs1[f];
                #pragma unroll 4
                for (int k4 = 0; k4 < 16; ++k4) {
                    const float4 xq = xr[k4];
                    const int k = k4 * 4;
                    a2 = fmaf(xq.x, Ws1[(k + 0) * 32 + f], a2);
                    a2 = fmaf(xq.y, Ws1[(k + 1) * 32 + f], a2);
                    a2 = fmaf(xq.z, Ws1[(k + 2) * 32 + f], a2);
                    a2 = fmaf(xq.w, Ws1[(k + 3) * 32 + f], a2);
                }
                sb[w][f] = fmaxf(a2, 0.0f);
            } else {
                const int j2 = f - 32;
                float a2 = bt1[j2];
                #pragma unroll 4
                for (int k4 = 0; k4 < 16; ++k4) {
                    const float4 xq = xr[k4];
                    const int k = k4 * 4;
                    a2 = fmaf(xq.x, Wt1[(k + 0) * 32 + j2], a2);
                    a2 = fmaf(xq.y, Wt1[(k + 1) * 32 + j2], a2);
                    a2 = fmaf(xq.z, Wt1[(k + 2) * 32 + j2], a2);
                    a2 = fmaf(xq.w, Wt1[(k + 3) * 32 + j2], a2);
                }
                sb[w][32 + j2] = fmaxf(a2, 0.0f);
            }
        }
        // heads stage 2: sb -> out (verified shape)
        {
            if (f == 0) {
                float a2 = bs2[0];
                #pragma unroll 8
                for (int j2 = 0; j2 < 32; ++j2)
                    a2 = fmaf(sb[w][j2], Ws2[j2], a2);
                out_scores[node] = a2;
            } else if (f >= 1 && f < 5) {
                const int c = f - 1;
                float a2 = bt2[c];
                #pragma unroll 8
                for (int j2 = 0; j2 < 32; ++j2)
                    a2 = fmaf(sb[w][32 + j2], Wt2[j2 * 4 + c], a2);
                out_types[node * 4 + c] = a2;
            }
        }
    }
}

extern "C" void kernel_launch(void* const* d_in, const int* in_sizes, int n_in,
                              void* d_out, int out_size, void* d_ws, size_t ws_size,
                              hipStream_t stream)
{
    const float* x   = (const float*)d_in[0];
    const int*   adj = (const int*)  d_in[1];   // [2, E]: src = adj[0:E], dst = adj[E:2E]
    const float* W1  = (const float*)d_in[2];
    const float* b1  = (const float*)d_in[3];
    const float* W2  = (const float*)d_in[4];
    const float* b2  = (const float*)d_in[5];
    const float* Wf1 = (const float*)d_in[6];
    const float* bf1 = (const float*)d_in[7];
    const float* Wf2 = (const float*)d_in[8];
    const float* bf2 = (const float*)d_in[9];
    const float* Ws1 = (const float*)d_in[10];
    const float* bs1 = (const float*)d_in[11];
    const float* Ws2 = (const float*)d_in[12];
    const float* bs2 = (const float*)d_in[13];
    const float* Wt1 = (const float*)d_in[14];
    const float* bt1 = (const float*)d_in[15];
    const float* Wt2 = (const float*)d_in[16];
    const float* bt2 = (const float*)d_in[17];

    float* out_scores = (float*)d_out;          // [N]
    float* out_types  = out_scores + NN;        // [N,4]

    // ws: staging [NB*ECAP u32] | h16 [NN*H half] | bfill [NB]
    unsigned* staging = (unsigned*)d_ws;
    __half*   h16     = (__half*)(staging + (size_t)NB * ECAP);
    int*      bfill   = (int*)(h16 + (size_t)NN * H);

    const int* src = adj;
    const int* dst = adj + NE;

    hipMemsetAsync(bfill, 0, NB * sizeof(int), stream);

    enc_part_kernel<<<NPBLK + ENCB, 1024, 0, stream>>>(x, W1, b1, W2, b2,
                                                       src, dst, bfill, staging, h16);
    sort_gather_kernel<<<NB, 1024, 0, stream>>>(h16, bfill, staging,
                                                Wf1, bf1, Wf2, bf2,
                                                Ws1, bs1, Ws2, bs2,
                                                Wt1, bt1, Wt2, bt2,
                                                out_scores, out_types);
}

// Round 16
// 440.827 us; speedup vs baseline: 1.1796x; 1.1796x over previous
//
#include <hip/hip_runtime.h>
#include <hip/hip_fp16.h>

#define NN 100000
#define NE 3200000
#define H  64

#define BSHIFT 7
#define BNODES 128
#define NB ((NN + BNODES - 1) / BNODES)          // 782 buckets

#define PTHREADS 1024
#define PCHUNK   8192
#define PEPT     (PCHUNK / PTHREADS)             // 8
#define NPBLK    ((NE + PCHUNK - 1) / PCHUNK)    // 391 partition blocks

#define ENCB (NN / 16)                           // 6250 encoder blocks (16 nodes @1024thr)

#define ECAP 6144                                // fixed per-bucket slot (mean 4092, sd ~64)

// ---- dispatch 2: heterogeneous — partition blocks [0,NPBLK) + encoder blocks ----
// (byte-identical to R15-verified enc_part_kernel)
__global__ __launch_bounds__(1024) void enc_part_kernel(
    const float* __restrict__ x,
    const float* __restrict__ W1, const float* __restrict__ b1,
    const float* __restrict__ W2, const float* __restrict__ b2,
    const int* __restrict__ src, const int* __restrict__ dst,
    int* __restrict__ bfill, unsigned* __restrict__ staging,
    __half* __restrict__ h16)
{
    __shared__ unsigned stage[PCHUNK];   // 32 KB
    __shared__ int gpos[PCHUNK];         // 32 KB
    __shared__ int lh[NB];
    __shared__ int lcur[NB];
    __shared__ int gbase[NB];
    __shared__ int wtot[16];
    __shared__ float sh1[16][H];         // 4 KB

    const int t = threadIdx.x;

    if (blockIdx.x < NPBLK) {
        // ---------------- partition path (verified R14/R15 body) --------------------
        const int lane = t & 63;
        const int wid  = t >> 6;
        const int cbase = blockIdx.x * PCHUNK;
        const int cnt = min(PCHUNK, NE - cbase);

        for (int i = t; i < NB; i += PTHREADS) lh[i] = 0;
        __syncthreads();

        unsigned ent[PEPT];
        int bkt[PEPT];
        #pragma unroll
        for (int j = 0; j < PEPT; ++j) {
            const int idx = t + j * PTHREADS;
            if (idx < cnt) {
                const int s_ = src[cbase + idx];
                const int d_ = dst[cbase + idx];
                bkt[j] = s_ >> BSHIFT;
                ent[j] = (unsigned)d_ | ((unsigned)(s_ & (BNODES - 1)) << 17);
                atomicAdd(&lh[bkt[j]], 1);
            } else bkt[j] = -1;
        }
        __syncthreads();

        const int hv = (t < NB) ? lh[t] : 0;
        int incl = hv;
        #pragma unroll
        for (int off = 1; off < 64; off <<= 1) {
            const int n = __shfl_up(incl, off);
            if (lane >= off) incl += n;
        }
        if (lane == 63) wtot[wid] = incl;
        __syncthreads();
        if (wid == 0 && lane < 16) {
            const int v = wtot[lane];
            int s2 = v;
            #pragma unroll
            for (int off = 1; off < 16; off <<= 1) {
                const int n = __shfl_up(s2, off);
                if (lane >= off) s2 += n;
            }
            wtot[lane] = s2 - v;    // exclusive wave offsets
        }
        __syncthreads();
        if (t < NB) {
            const int excl = incl - hv + wtot[wid];
            lh[t]   = excl;
            lcur[t] = excl;
            gbase[t] = t * ECAP + ((hv > 0) ? atomicAdd(&bfill[t], hv) : 0);
        }
        __syncthreads();

        #pragma unroll
        for (int j = 0; j < PEPT; ++j) {
            if (bkt[j] >= 0) {
                const int lp = atomicAdd(&lcur[bkt[j]], 1);
                stage[lp] = ent[j];
                gpos[lp]  = gbase[bkt[j]] + (lp - lh[bkt[j]]);
            }
        }
        __syncthreads();

        for (int i = t; i < cnt; i += PTHREADS)
            staging[gpos[i]] = stage[i];
    } else {
        // ---------------- encoder path (verified; 16 nodes/block) -------------------
        const int slot = t >> 6;
        const int f    = t & 63;
        const int node = (blockIdx.x - NPBLK) * 16 + slot;   // < NN always
        {
            float acc = b1[f];
            #pragma unroll
            for (int k = 0; k < 6; ++k)
                acc = fmaf(x[node * 6 + k], W1[k * H + f], acc);
            sh1[slot][f] = fmaxf(acc, 0.0f);
        }
        __syncthreads();
        {
            float acc = b2[f];
            #pragma unroll 8
            for (int k = 0; k < H; ++k)
                acc = fmaf(sh1[slot][k], W2[k * H + f], acc);
            h16[node * H + f] = __float2half(acc);
        }
    }
}

// ---- dispatch 3: bucket sort + per-node offs/counts (byte-identical R14-verified) --
__global__ __launch_bounds__(1024) void bucket_sort_kernel(
    const unsigned* __restrict__ staging, const int* __restrict__ bfill,
    int* __restrict__ sdst, int* __restrict__ offs, int* __restrict__ counts)
{
    __shared__ int ldst[ECAP];           // 24 KB
    __shared__ int cntS[BNODES];
    __shared__ int scanS[BNODES];
    __shared__ int lstart[BNODES];
    __shared__ int lcur[BNODES];
    const int t = threadIdx.x;
    const int b = blockIdx.x;
    const int base0 = b * ECAP;
    const int ecnt  = bfill[b];

    if (t < BNODES) cntS[t] = 0;
    __syncthreads();
    for (int i = t; i < ecnt; i += 1024)
        atomicAdd(&cntS[staging[base0 + i] >> 17], 1);
    __syncthreads();
    if (t < BNODES) scanS[t] = cntS[t];
    __syncthreads();
    for (int off = 1; off < BNODES; off <<= 1) {
        int xv = 0;
        if (t >= off && t < BNODES) xv = scanS[t - off];
        __syncthreads();
        if (t >= off && t < BNODES) scanS[t] += xv;
        __syncthreads();
    }
    if (t < BNODES) {
        const int st = scanS[t] - cntS[t];
        lstart[t] = st;
        lcur[t]   = st;
    }
    __syncthreads();
    for (int i = t; i < ecnt; i += 1024) {
        const unsigned ev = staging[base0 + i];
        const int lp = atomicAdd(&lcur[(int)(ev >> 17)], 1);
        ldst[lp] = (int)(ev & 0x1FFFFu);
    }
    __syncthreads();
    for (int i = t; i < ecnt; i += 1024)
        sdst[base0 + i] = ldst[i];       // contiguous coalesced segment write

    const int nbase = b * BNODES;
    if (t < BNODES && nbase + t < NN) {
        offs[nbase + t]   = base0 + lstart[t];
        counts[nbase + t] = cntS[t];
    }
}

// ---- dispatch 4: fused gather(mean)+MLP+heads — BYTE-IDENTICAL to R9/R14-verified --
__global__ __launch_bounds__(256) void gather_head_kernel(
    const __half* __restrict__ h16,
    const int* __restrict__ counts, const int* __restrict__ offs,
    const int* __restrict__ sdst,
    const float* __restrict__ Wf1, const float* __restrict__ bf1,
    const float* __restrict__ Wf2, const float* __restrict__ bf2,
    const float* __restrict__ Ws1, const float* __restrict__ bs1,
    const float* __restrict__ Ws2, const float* __restrict__ bs2,
    const float* __restrict__ Wt1, const float* __restrict__ bt1,
    const float* __restrict__ Wt2, const float* __restrict__ bt2,
    float* __restrict__ out_scores, float* __restrict__ out_types)
{
    __shared__ float sa[4][H];
    __shared__ float sb[4][H];
    const int tid  = threadIdx.x;
    const int slot = tid >> 6;
    const int f    = tid & 63;
    const int node = blockIdx.x * 4 + slot;   // grid 25000 -> node < NN always

    const int deg   = counts[node];
    const int start = offs[node];

    const float selfv = __half2float(h16[((size_t)node << 6) + f]);  // issued early

    float acc = 0.0f;
    for (int base = 0; base < deg; base += 64) {
        const int m = min(64, deg - base);
        int idx = 0;
        if (base + f < deg) idx = sdst[start + base + f];   // coalesced vector load

        int jj = 0;
        for (; jj + 16 <= m; jj += 16) {                    // 16 uniform rows in flight
            __half hv[16];
            #pragma unroll
            for (int u = 0; u < 16; ++u) {
                const int d = __shfl(idx, jj + u);
                hv[u] = h16[((size_t)d << 6) + f];
            }
            #pragma unroll
            for (int u = 0; u < 16; ++u)
                acc += __half2float(hv[u]);
        }
        if (jj + 8 <= m) {                                  // 8-deep tail
            __half hv[8];
            #pragma unroll
            for (int u = 0; u < 8; ++u) {
                const int d = __shfl(idx, jj + u);
                hv[u] = h16[((size_t)d << 6) + f];
            }
            #pragma unroll
            for (int u = 0; u < 8; ++u)
                acc += __half2float(hv[u]);
            jj += 8;
        }
        for (; jj < m; ++jj) {
            const int d = __shfl(idx, jj);
            acc += __half2float(h16[((size_t)d << 6) + f]);
        }
    }

    const float inv = 1.0f / fmaxf((float)deg, 1.0f);
    sa[slot][f] = selfv + acc * inv;
    __syncthreads();

    {
        float a2 = bf1[f];
        #pragma unroll 8
        for (int k = 0; k < H; ++k)
            a2 = fmaf(sa[slot][k], Wf1[k * H + f], a2);
        sb[slot][f] = fmaxf(a2, 0.0f);
    }
    __syncthreads();

    {
        float a2 = bf2[f];
        #pragma unroll 8
        for (int k = 0; k < H; ++k)
            a2 = fmaf(sb[slot][k], Wf2[k * H + f], a2);
        sa[slot][f] = fmaxf(a2, 0.0f);
    }
    __syncthreads();

    {
        if (f < 32) {
            float a2 = bs1[f];
            #pragma unroll 8
            for (int k = 0; k < H; ++k)
                a2 = fmaf(sa[slot][k], Ws1[k * 32 + f], a2);
            sb[slot][f] = fmaxf(a2, 0.0f);
        } else {
            const int jj = f - 32;
            float a2 = bt1[jj];
            #pragma unroll 8
            for (int k = 0; k < H; ++k)
                a2 = fmaf(sa[slot][k], Wt1[k * 32 + jj], a2);
            sb[slot][32 + jj] = fmaxf(a2, 0.0f);
        }
    }
    __syncthreads();

    {
        if (f == 0) {
            float a2 = bs2[0];
            #pragma unroll 8
            for (int jj = 0; jj < 32; ++jj)
                a2 = fmaf(sb[slot][jj], Ws2[jj], a2);
            out_scores[node] = a2;
        } else if (f >= 1 && f < 5) {
            const int c = f - 1;
            float a2 = bt2[c];
            #pragma unroll 8
            for (int jj = 0; jj < 32; ++jj)
                a2 = fmaf(sb[slot][32 + jj], Wt2[jj * 4 + c], a2);
            out_types[node * 4 + c] = a2;
        }
    }
}

extern "C" void kernel_launch(void* const* d_in, const int* in_sizes, int n_in,
                              void* d_out, int out_size, void* d_ws, size_t ws_size,
                              hipStream_t stream)
{
    const float* x   = (const float*)d_in[0];
    const int*   adj = (const int*)  d_in[1];   // [2, E]: src = adj[0:E], dst = adj[E:2E]
    const float* W1  = (const float*)d_in[2];
    const float* b1  = (const float*)d_in[3];
    const float* W2  = (const float*)d_in[4];
    const float* b2  = (const float*)d_in[5];
    const float* Wf1 = (const float*)d_in[6];
    const float* bf1 = (const float*)d_in[7];
    const float* Wf2 = (const float*)d_in[8];
    const float* bf2 = (const float*)d_in[9];
    const float* Ws1 = (const float*)d_in[10];
    const float* bs1 = (const float*)d_in[11];
    const float* Ws2 = (const float*)d_in[12];
    const float* bs2 = (const float*)d_in[13];
    const float* Wt1 = (const float*)d_in[14];
    const float* bt1 = (const float*)d_in[15];
    const float* Wt2 = (const float*)d_in[16];
    const float* bt2 = (const float*)d_in[17];

    float* out_scores = (float*)d_out;          // [N]
    float* out_types  = out_scores + NN;        // [N,4]

    // ws: staging [NB*ECAP u32] | sdst [NB*ECAP] | h16 [NN*H half] | counts [NN]
    //     | offs [NN] | bfill [NB]
    unsigned* staging = (unsigned*)d_ws;
    int*      sdst    = (int*)(staging + (size_t)NB * ECAP);
    __half*   h16     = (__half*)(sdst + (size_t)NB * ECAP);
    int*      counts  = (int*)(h16 + (size_t)NN * H);
    int*      offs    = counts + NN;
    int*      bfill   = offs + NN;

    const int* src = adj;
    const int* dst = adj + NE;

    hipMemsetAsync(bfill, 0, NB * sizeof(int), stream);

    enc_part_kernel<<<NPBLK + ENCB, 1024, 0, stream>>>(x, W1, b1, W2, b2,
                                                       src, dst, bfill, staging, h16);
    bucket_sort_kernel<<<NB, 1024, 0, stream>>>(staging, bfill, sdst, offs, counts);
    gather_head_kernel<<<NN / 4, 256, 0, stream>>>(h16, counts, offs, sdst,
                                                   Wf1, bf1, Wf2, bf2,
                                                   Ws1, bs1, Ws2, bs2,
                                                   Wt1, bt1, Wt2, bt2,
                                                   out_scores, out_types);
}